// Round 2
// 502.523 us; speedup vs baseline: 1.0013x; 1.0013x over previous
//
#include <hip/hip_runtime.h>
#include <cstdint>
#include <cstddef>

// Problem constants (from reference): B=16, H=32, KVH=8, D=128, CACHE=4096
#define BATCH 16
#define HQ 32
#define KVHN 8
#define NREP 4
#define DIM 128
#define CACHE_LEN 4096
#define STATE_POS 128                    // cached positions per partial state (one wave)
#define NSTATE (CACHE_LEN / STATE_POS)   // 32

// ---------------------------------------------------------------------------
// Kernel 1: per-(b,kvh,state) partial flash-decode over 128 cached positions.
// One wave = 4 groups of 16 lanes; group g handles s = start + 4i + g, lane sl
// owns dims [4sl..4sl+3] and [64+4sl..64+4sl+3] (dense 256B chunks per row).
// Round-6 changes vs round-5 (503 us):
//  * quad-transpose score reduction: butterfly xor 1,2 on all 4 heads (DPP),
//    then lane selects head sl&3 and finishes xor 4,8 on ONE value.
//    24 cross-lane ops -> 13, ds_swizzle 8 -> 2 per iter. Bit-identical tree.
//  * explicit 1-deep register prefetch of next K/V rows (clamped to the
//    state's own last row -> never OOB) to keep VMEM loaded across the body.
//  * k/v scalers staged to LDS once (removes 64 in-loop global dwords/wave).
//  * state swizzle (x + 5b + kvh)&31 so each CU gets a mix of full/empty
//    states (states 0-7 are always full, 28-31 nearly always empty).
// (History: sl*8 stripe was 50% dense -> 2x VMEM; wave packing +
// launch_bounds(256,4) spilled to scratch. 1-wave blocks, no reg cap.)
// Round-7: resubmission of round-6 unchanged — the round-6 bench died with
// "MI355X container failed twice" (infra acquire failure, no profile); code
// audit found no OOB/hang/capture issue. Need a clean measurement.
// ---------------------------------------------------------------------------
__global__ __launch_bounds__(64) void attn_partial(
    const float* __restrict__ xq,
    const float* __restrict__ fcos,
    const float* __restrict__ fsin,
    const float* __restrict__ k_scaler,
    const float* __restrict__ v_scaler,
    const int*   __restrict__ cache_k,
    const int*   __restrict__ cache_v,
    const int*   __restrict__ input_pos,
    float* __restrict__ ws_acc,   // [B][KVH][NSTATE][4][DIM]
    float* __restrict__ ws_ml)    // [B][KVH][NSTATE][4][2]  (m,l)
{
    const int kvh   = blockIdx.y;
    const int b     = blockIdx.z;
    const int state = ((int)blockIdx.x + 5 * b + kvh) & (NSTATE - 1);
    const int pos   = input_pos[b];          // cached positions are s < pos
    const int start = state * STATE_POS;
    if (start >= pos) return;                // state empty -> combine skips it

    const int lane = threadIdx.x;            // 0..63
    const int g    = lane >> 4;              // position group 0..3
    const int sl   = lane & 15;              // dim slice
    const int dA   = sl * 4;                 // dims dA..dA+3
    const int dB   = 64 + sl * 4;            // dims dB..dB+3

    const int send = min(start + STATE_POS, pos);
    const float rsD = 0.088388347648318447f; // 1/sqrt(128)

    // RoPE'd q fragment for this lane's 8 dims, pre-scaled by 1/sqrt(D).
    float q[4][8];
    {
        float2 cA = *(const float2*)(fcos + b * 64 + 2 * sl);
        float2 sA = *(const float2*)(fsin + b * 64 + 2 * sl);
        float2 cB = *(const float2*)(fcos + b * 64 + 32 + 2 * sl);
        float2 sB = *(const float2*)(fsin + b * 64 + 32 + 2 * sl);
        cA.x *= rsD; cA.y *= rsD; cB.x *= rsD; cB.y *= rsD;
        sA.x *= rsD; sA.y *= rsD; sB.x *= rsD; sB.y *= rsD;
        #pragma unroll
        for (int r = 0; r < 4; ++r) {
            const float* qp = xq + ((size_t)(b * HQ + kvh * NREP + r)) * DIM;
            const float4 x0 = *(const float4*)(qp + dA);
            const float4 x1 = *(const float4*)(qp + dB);
            q[r][0] = x0.x * cA.x - x0.y * sA.x;
            q[r][1] = x0.x * sA.x + x0.y * cA.x;
            q[r][2] = x0.z * cA.y - x0.w * sA.y;
            q[r][3] = x0.z * sA.y + x0.w * cA.y;
            q[r][4] = x1.x * cB.x - x1.y * sB.x;
            q[r][5] = x1.x * sB.x + x1.y * cB.x;
            q[r][6] = x1.z * cB.y - x1.w * sB.y;
            q[r][7] = x1.z * sB.y + x1.w * cB.y;
        }
    }

    const int bk = b * KVHN + kvh;
    const int*   __restrict__ kb  = cache_k + (size_t)bk * CACHE_LEN * DIM;
    const int*   __restrict__ vbp = cache_v + (size_t)bk * CACHE_LEN * DIM;
    const float* __restrict__ ks  = k_scaler + (size_t)bk * CACHE_LEN;
    const float* __restrict__ vs  = v_scaler + (size_t)bk * CACHE_LEN;

    __shared__ float4 ssc4[STATE_POS];       // per-position scores, 4 heads
    __shared__ float  sks_l[STATE_POS];      // staged k scalers
    __shared__ float  svs_l[STATE_POS];      // staged v scalers

    // stage scalers once (always in-bounds: start+127 <= 4095)
    sks_l[lane]      = ks[start + lane];
    sks_l[64 + lane] = ks[start + 64 + lane];
    svs_l[lane]      = vs[start + lane];
    svs_l[64 + lane] = vs[start + 64 + lane];

    // loop-invariant lane predicates (compares hoisted out of the hot loop)
    const bool h1  = (sl & 3) == 1;
    const bool h2  = (sl & 3) == 2;
    const bool h3  = (sl & 3) == 3;
    const bool wlo = sl < 4;                 // score-writer lanes
    const int  slast = start + 124 + g;      // this lane-group's last row

    float mloc = -1e30f;                     // running max of head (sl&3)

    // ---------------- K pass: scores -> LDS, running max ----------------
    {
        const int* kp0 = kb + (size_t)(start + g) * DIM;
        int4 ka = *(const int4*)(kp0 + dA);
        int4 kc = *(const int4*)(kp0 + dB);
        #pragma unroll 4
        for (int i = 0; i < STATE_POS / 4; ++i) {
            const int s  = start + i * 4 + g;
            const int sn = min(s + 4, slast);            // prefetch row (in-bounds)
            const int* kpn = kb + (size_t)sn * DIM;
            const int4 na = *(const int4*)(kpn + dA);
            const int4 nc = *(const int4*)(kpn + dB);

            const float k0 = (float)ka.x, k1 = (float)ka.y, k2 = (float)ka.z, k3 = (float)ka.w;
            const float k4 = (float)kc.x, k5 = (float)kc.y, k6 = (float)kc.z, k7 = (float)kc.w;
            float p[4];
            #pragma unroll
            for (int r = 0; r < 4; ++r) {
                p[r] = q[r][0] * k0 + q[r][1] * k1 + q[r][2] * k2 + q[r][3] * k3
                     + q[r][4] * k4 + q[r][5] * k5 + q[r][6] * k6 + q[r][7] * k7;
            }
            // quad-level butterfly on all 4 heads (xor 1,2: DPP quad_perm)
            #pragma unroll
            for (int r = 0; r < 4; ++r) {
                p[r] += __shfl_xor(p[r], 1, 64);
                p[r] += __shfl_xor(p[r], 2, 64);
            }
            // lane takes head (sl&3), finishes cross-quad reduce on one value
            float t = p[0];
            t = h1 ? p[1] : t;
            t = h2 ? p[2] : t;
            t = h3 ? p[3] : t;
            t += __shfl_xor(t, 4, 64);
            t += __shfl_xor(t, 8, 64);
            // all 16 lanes of the group now hold head (sl&3)'s full score
            const float sc = (s < send) ? t * sks_l[i * 4 + g] : -1e30f;
            mloc = fmaxf(mloc, sc);
            if (wlo) ((float*)ssc4)[(i * 4 + g) * 4 + sl] = sc;
            ka = na; kc = nc;
        }
    }

    // per-head wave max: values are identical across quads already, reduce
    // across the 4 position-groups (lane bits 4,5), then broadcast heads.
    mloc = fmaxf(mloc, __shfl_xor(mloc, 16, 64));
    mloc = fmaxf(mloc, __shfl_xor(mloc, 32, 64));
    float mh[4];
    #pragma unroll
    for (int r = 0; r < 4; ++r) mh[r] = __shfl(mloc, r, 64); // lane r holds head r
    __syncthreads();

    // ---------------- V pass: exp + plain accumulate ----------------
    float l[4] = {0.f, 0.f, 0.f, 0.f};
    float acc[4][8] = {};
    {
        const int* vp0 = vbp + (size_t)(start + g) * DIM;
        int4 va = *(const int4*)(vp0 + dA);
        int4 vc = *(const int4*)(vp0 + dB);
        #pragma unroll 4
        for (int i = 0; i < STATE_POS / 4; ++i) {
            const int s  = start + i * 4 + g;
            const int sn = min(s + 4, slast);
            const int* vpn = vbp + (size_t)sn * DIM;
            const int4 na = *(const int4*)(vpn + dA);
            const int4 nc = *(const int4*)(vpn + dB);

            const float vsc = svs_l[i * 4 + g];
            const float4 sc4 = ssc4[i * 4 + g];  // broadcast within group
            const float v0 = (float)va.x, v1 = (float)va.y, v2 = (float)va.z, v3 = (float)va.w;
            const float v4 = (float)vc.x, v5 = (float)vc.y, v6 = (float)vc.z, v7 = (float)vc.w;
            const float scr[4] = {sc4.x, sc4.y, sc4.z, sc4.w};
            #pragma unroll
            for (int r = 0; r < 4; ++r) {
                const float pr = __expf(scr[r] - mh[r]);  // invalid: exp(-1e30)=0
                l[r] += pr;
                const float pv = pr * vsc;
                acc[r][0] += pv * v0; acc[r][1] += pv * v1;
                acc[r][2] += pv * v2; acc[r][3] += pv * v3;
                acc[r][4] += pv * v4; acc[r][5] += pv * v5;
                acc[r][6] += pv * v6; acc[r][7] += pv * v7;
            }
            va = na; vc = nc;
        }
    }

    // merge the 4 group states: plain sums (max was wave-uniform already)
    #pragma unroll
    for (int mask = 16; mask <= 32; mask <<= 1) {
        #pragma unroll
        for (int r = 0; r < 4; ++r) {
            l[r] += __shfl_xor(l[r], mask, 64);
            #pragma unroll
            for (int c = 0; c < 8; ++c) acc[r][c] += __shfl_xor(acc[r][c], mask, 64);
        }
    }

    if (g == 0) {                            // lanes 0..15 hold the totals
        float* abase = ws_acc + (((size_t)bk * NSTATE + state) * 4) * DIM;
        #pragma unroll
        for (int r = 0; r < 4; ++r) {
            float4 a0 = make_float4(acc[r][0], acc[r][1], acc[r][2], acc[r][3]);
            float4 a1 = make_float4(acc[r][4], acc[r][5], acc[r][6], acc[r][7]);
            *(float4*)(abase + r * DIM + dA) = a0;
            *(float4*)(abase + r * DIM + dB) = a1;
        }
        if (sl == 0) {
            float* mlb = ws_ml + ((size_t)bk * NSTATE + state) * 8;
            #pragma unroll
            for (int r = 0; r < 4; ++r) { mlb[2 * r] = mh[r]; mlb[2 * r + 1] = l[r]; }
        }
    }
}

// ---------------------------------------------------------------------------
// Kernel 2: per-(b,kvh) combine. Recomputes RoPE q, quantizes the new token
// (exactly replicating the reference: max|x|/127+1e-8, round-half-even, clip),
// adds it as one extra softmax state, merges all partials, writes f32 out.
// (Unchanged from round-5.)
// ---------------------------------------------------------------------------
__global__ __launch_bounds__(256) void attn_combine(
    const float* __restrict__ xq,
    const float* __restrict__ xk,
    const float* __restrict__ xv,
    const float* __restrict__ fcos,
    const float* __restrict__ fsin,
    const int*   __restrict__ input_pos,
    const float* __restrict__ ws_acc,
    const float* __restrict__ ws_ml,
    float* __restrict__ out)
{
    const int bk  = blockIdx.x;
    const int b   = bk >> 3;
    const int kvh = bk & 7;
    const int pos = input_pos[b];
    const int nst = min(NSTATE, (pos + STATE_POS - 1) / STATE_POS);

    const int t    = threadIdx.x;
    const int lane = t & 63;
    const int w    = t >> 6;          // wave id 0..3

    __shared__ float sq[4][DIM];      // RoPE'd q
    __shared__ float skq[DIM];        // rope'd k, then quantized k (int-valued)
    __shared__ float svd[DIM];        // dequantized new v  (v_s * v_q)
    __shared__ float sml[NSTATE][8];  // staged (m,l) per state per head
    __shared__ float ssc[4];          // new-token score per head
    __shared__ float sks, svs;

    const float rsD = 0.088388347648318447f;

    // q RoPE: thread (w=r, lane=p) handles pair p of head r
    {
        const float c  = fcos[b * 64 + lane];
        const float s  = fsin[b * 64 + lane];
        const size_t qb = ((size_t)(b * HQ + kvh * NREP + w)) * DIM;
        const float xe = xq[qb + 2 * lane];
        const float xo = xq[qb + 2 * lane + 1];
        sq[w][2 * lane]     = xe * c - xo * s;
        sq[w][2 * lane + 1] = xe * s + xo * c;
    }
    // k RoPE (wave 0)
    if (w == 0) {
        const float c  = fcos[b * 64 + lane];
        const float s  = fsin[b * 64 + lane];
        const size_t kbb = ((size_t)(b * KVHN + kvh)) * DIM;
        const float xe = xk[kbb + 2 * lane];
        const float xo = xk[kbb + 2 * lane + 1];
        skq[2 * lane]     = xe * c - xo * s;
        skq[2 * lane + 1] = xe * s + xo * c;
    }
    // stage (m,l): only first nst*8 floats are valid in ws
    for (int j = t; j < nst * 8; j += 256)
        sml[j >> 3][j & 7] = ws_ml[(size_t)bk * NSTATE * 8 + j];
    __syncthreads();

    // scalers: k_s from rope'd k (wave 0), v_s from xv (wave 1)
    if (w == 0) {
        float a = fmaxf(fabsf(skq[lane]), fabsf(skq[64 + lane]));
        #pragma unroll
        for (int mask = 32; mask; mask >>= 1) a = fmaxf(a, __shfl_xor(a, mask, 64));
        if (lane == 0) sks = a / 127.0f + 1e-8f;
    } else if (w == 1) {
        const size_t vbb = ((size_t)(b * KVHN + kvh)) * DIM;
        float a = fmaxf(fabsf(xv[vbb + lane]), fabsf(xv[vbb + 64 + lane]));
        #pragma unroll
        for (int mask = 32; mask; mask >>= 1) a = fmaxf(a, __shfl_xor(a, mask, 64));
        if (lane == 0) svs = a / 127.0f + 1e-8f;
    }
    __syncthreads();

    // quantize k, dequantize new v
    if (t < DIM) {
        skq[t] = fminf(fmaxf(rintf(skq[t] / sks), -127.f), 127.f);
    } else {
        const int d = t - DIM;
        const size_t vbb = ((size_t)(b * KVHN + kvh)) * DIM;
        const float vq = fminf(fmaxf(rintf(xv[vbb + d] / svs), -127.f), 127.f);
        svd[d] = vq * svs;
    }
    __syncthreads();

    // new-token score for head w
    {
        float sum = sq[w][lane] * skq[lane] + sq[w][64 + lane] * skq[64 + lane];
        #pragma unroll
        for (int mask = 32; mask; mask >>= 1) sum += __shfl_xor(sum, mask, 64);
        if (lane == 0) ssc[w] = sum * rsD * sks;
    }
    __syncthreads();

    // final combine: thread (w=r, lane=db) handles dims db and db+64
    const int r  = w;
    const int db = lane;
    float M = ssc[r];
    for (int s2 = 0; s2 < nst; ++s2) M = fmaxf(M, sml[s2][2 * r]);
    const float pn = __expf(ssc[r] - M);
    float L  = pn;
    float o0 = pn * svd[db];
    float o1 = pn * svd[db + 64];
    const float* ab = ws_acc + (size_t)bk * NSTATE * 4 * DIM;
    for (int s2 = 0; s2 < nst; ++s2) {
        const float al = __expf(sml[s2][2 * r] - M);
        L  += sml[s2][2 * r + 1] * al;
        o0 += ab[((size_t)(s2 * 4 + r)) * DIM + db]      * al;
        o1 += ab[((size_t)(s2 * 4 + r)) * DIM + db + 64] * al;
    }
    const float invL = 1.0f / L;
    float* ob = out + ((size_t)(b * HQ + kvh * NREP + r)) * DIM;
    ob[db]      = o0 * invL;
    ob[db + 64] = o1 * invL;
}

extern "C" void kernel_launch(void* const* d_in, const int* in_sizes, int n_in,
                              void* d_out, int out_size, void* d_ws, size_t ws_size,
                              hipStream_t stream)
{
    const float* xq        = (const float*)d_in[0];
    const float* xk        = (const float*)d_in[1];
    const float* xv        = (const float*)d_in[2];
    const float* fcos      = (const float*)d_in[3];
    const float* fsin      = (const float*)d_in[4];
    const float* k_scaler  = (const float*)d_in[5];
    const float* v_scaler  = (const float*)d_in[6];
    const int*   cache_k   = (const int*)d_in[7];
    const int*   cache_v   = (const int*)d_in[8];
    const int*   input_pos = (const int*)d_in[9];
    float* out = (float*)d_out;

    float* ws_acc = (float*)d_ws;                                     // 8 MiB
    float* ws_ml  = ws_acc + (size_t)BATCH * KVHN * NSTATE * 4 * DIM; // +128 KiB

    dim3 g1(NSTATE, KVHN, BATCH);
    attn_partial<<<g1, 64, 0, stream>>>(xq, fcos, fsin, k_scaler, v_scaler,
                                        cache_k, cache_v, input_pos, ws_acc, ws_ml);
    attn_combine<<<BATCH * KVHN, 256, 0, stream>>>(xq, xk, xv, fcos, fsin,
                                                   input_pos, ws_acc, ws_ml, out);
}